// Round 15
// baseline (40.094 us; speedup 1.0000x reference)
//
#include <hip/hip_runtime.h>
#include <hip/hip_bf16.h>
#include <math.h>

#define TT 2048
#define HH 512   // hidden = NUM_HEADS*DIM_KEY
#define NH 8
#define DK 64
#define WIN 16
#define NC 33    // 2*WIN+1

typedef __attribute__((ext_vector_type(8))) short bf16x8;
typedef __attribute__((ext_vector_type(4))) float f32x4;

__device__ inline ushort f2bf(float f) {   // RNE float -> bf16 bits
  uint u = __builtin_bit_cast(uint, f);
  return (ushort)((u + 0x7FFFu + ((u >> 16) & 1u)) >> 16);
}
__device__ inline ushort cvt1(float f) {   // compiler cast (v_cvt_pk capable)
  __hip_bfloat16 h = __float2bfloat16(f);
  return __builtin_bit_cast(ushort, h);
}

// ---------------- W fp32 -> bf16 pre-convert (weights only, 2 MB) ---------
__global__ __launch_bounds__(256) void cvt_w(
    const float* __restrict__ Wq, const float* __restrict__ Wk,
    ushort* __restrict__ Wqb, ushort* __restrict__ Wkb)
{
  const int id = blockIdx.x * 256 + threadIdx.x;   // 65536 tasks x 8 elems
  const float* src = (id < 32768) ? Wq : Wk;
  ushort* dst = (id < 32768) ? Wqb : Wkb;
  const int off = (id & 32767) * 8;
  float4 x = *(const float4*)(src + off);
  float4 y = *(const float4*)(src + off + 4);
  union { ushort s[8]; uint4 v; } pk;
  pk.s[0]=cvt1(x.x); pk.s[1]=cvt1(x.y); pk.s[2]=cvt1(x.z); pk.s[3]=cvt1(x.w);
  pk.s[4]=cvt1(y.x); pk.s[5]=cvt1(y.y); pk.s[6]=cvt1(y.z); pk.s[7]=cvt1(y.w);
  *(uint4*)(dst + off) = pk.v;
}

// ---------------- projection GEMM (bf16 MFMA): C = A @ W^T + b, bf16 out --
// MLP round: cold-cache replays (harness reset() evicts L3 between timed
// replays) make proj HBM-latency-bound; prior grids gave <=4 blocks/CU
// (R11: Occ 32%, HBM 29%). PBM=32 halves the tile -> 2048 blocks = 8/CU,
// 2x chip-wide outstanding loads. LDS 20KB; acc[1][4] (~40 VGPR).
// 16B-granule XOR swizzle kept (swizzled source, linear dest, swizzled read).
#define PBM 32
#define PBN 128
#define PBK 64

__global__ __launch_bounds__(256, 8) void proj_mfma(
    const float* __restrict__ Aq, const float* __restrict__ Ak,
    const ushort* __restrict__ Wqb, const ushort* __restrict__ Wkb,
    const float* __restrict__ bq, const float* __restrict__ bk,
    ushort* __restrict__ Qp, ushort* __restrict__ Kp)
{
  __shared__ ushort As[PBM * PBK];   // 4 KB
  __shared__ ushort Ws[PBN * PBK];   // 16 KB

  const int z = blockIdx.z;
  const float*  A    = z ? Ak  : Aq;
  const ushort* Wb   = z ? Wkb : Wqb;
  const float*  bias = z ? bk  : bq;
  ushort*       C    = z ? Kp  : Qp;

  const int m0 = blockIdx.x * PBM;
  const int n0 = blockIdx.y * PBN;
  const int t  = threadIdx.x;
  const int l  = t & 63;
  const int w  = t >> 6;
  const int wr = (w >> 1) * 16;   // wave row offset (2 wave-rows of 16)
  const int wc = (w & 1) * 64;    // wave col offset (2 wave-cols of 64)
  const int lr = l & 15;
  const int hi = l >> 4;
  const int swz = lr & 7;         // fragment-row swizzle key

  f32x4 acc[4] = {};

  for (int k0 = 0; k0 < HH; k0 += PBK) {
    // ---- W: 128x64 = 1024 granules, 4 global_load_lds (swizzled src) ----
#pragma unroll
    for (int p = 0; p < 4; ++p) {
      const int u = p * 256 + t;
      const int r = u >> 3;
      const int g = (u & 7) ^ (r & 7);
      __builtin_amdgcn_global_load_lds(
          (const __attribute__((address_space(1))) uint*)
              (Wb + (size_t)(n0 + r) * HH + k0 + g * 8),
          (__attribute__((address_space(3))) uint*)(Ws + p * 2048 + w * 512),
          16, 0, 0);
    }
    // ---- A: 32x64 = 256 granules, 1/thread, fp32->bf16, linear dest ----
    {
      const int u = t;
      const int r = u >> 3;
      const int g = (u & 7) ^ (r & 7);
      const float* gp = A + (size_t)(m0 + r) * HH + k0 + g * 8;
      float4 x = ((const float4*)gp)[0], y = ((const float4*)gp)[1];
      union { ushort s[8]; uint4 v; } pk;
      pk.s[0]=cvt1(x.x); pk.s[1]=cvt1(x.y); pk.s[2]=cvt1(x.z); pk.s[3]=cvt1(x.w);
      pk.s[4]=cvt1(y.x); pk.s[5]=cvt1(y.y); pk.s[6]=cvt1(y.z); pk.s[7]=cvt1(y.w);
      *(uint4*)&As[u * 8] = pk.v;
    }
    __syncthreads();

#pragma unroll
    for (int kk = 0; kk < PBK; kk += 32) {
      const int gq = (kk >> 3) + hi;        // needed column granule
      bf16x8 af, bf[4];
      af = *(const bf16x8*)&As[(wr + lr) * PBK + ((gq ^ swz) * 8)];
#pragma unroll
      for (int n = 0; n < 4; ++n)
        bf[n] = *(const bf16x8*)&Ws[(wc + n * 16 + lr) * PBK + ((gq ^ swz) * 8)];
#pragma unroll
      for (int n = 0; n < 4; ++n)
        acc[n] = __builtin_amdgcn_mfma_f32_16x16x32_bf16(af, bf[n], acc[n], 0, 0, 0);
    }
    __syncthreads();
  }

  // ---- epilogue: D row=(l>>4)*4+q, col=l&15 (rounds 3-14 verified) ----
#pragma unroll
  for (int n = 0; n < 4; ++n) {
    const int col = n0 + wc + n * 16 + lr;
    const float bc = bias[col];
    const int rbase = m0 + wr + hi * 4;
#pragma unroll
    for (int q = 0; q < 4; ++q)
      C[(size_t)(rbase + q) * HH + col] = f2bf(acc[n][q] + bc);
  }
}

// ---------------- MFMA windowed attention + softmax + gather --------------
// One wave per (16-row tile, head); S[16][48] via 6 MFMAs, fragments direct
// from global; in-register softmax; scatter to gathered layout.
__global__ __launch_bounds__(256) void attn_mfma(
    const ushort* __restrict__ Q, const ushort* __restrict__ Kp,
    float* __restrict__ out)
{
  const int gw = blockIdx.x * 4 + (threadIdx.x >> 6);   // 0..4095
  const int h = gw & 7;
  const int tile = gw >> 3;          // 0..511
  const int b = tile >> 7;           // 128 row-tiles per batch
  const int i0 = (tile & 127) * 16;
  const int l = threadIdx.x & 63;
  const int lo = l & 15;             // fragment row/col lane index
  const int hi = l >> 4;             // k-slice / acc row-group

  int jb = i0 - WIN;                 // start(i0) = clip(i0-16,0,T-33)
  if (jb < 0) jb = 0;
  if (jb > TT - NC) jb = TT - NC;

  const size_t qbase = ((size_t)(b * TT + i0 + lo)) * HH + h * DK + hi * 8;
  bf16x8 aq0 = *(const bf16x8*)(Q + qbase);
  bf16x8 aq1 = *(const bf16x8*)(Q + qbase + 32);

  f32x4 acc[3] = {};
#pragma unroll
  for (int a = 0; a < 3; ++a) {
    int j = jb + a * 16 + lo;
    if (j > TT - 1) j = TT - 1;      // clamped loads get masked below
    const size_t kbase = ((size_t)(b * TT + j)) * HH + h * DK + hi * 8;
    bf16x8 bk0 = *(const bf16x8*)(Kp + kbase);
    bf16x8 bk1 = *(const bf16x8*)(Kp + kbase + 32);
    acc[a] = __builtin_amdgcn_mfma_f32_16x16x32_bf16(aq0, bk0, acc[a], 0, 0, 0);
    acc[a] = __builtin_amdgcn_mfma_f32_16x16x32_bf16(aq1, bk1, acc[a], 0, 0, 0);
  }

  float e[3][4];
  float inv[4];
#pragma unroll
  for (int q = 0; q < 4; ++q) {
    const int i = i0 + hi * 4 + q;
    const int j0 = jb + lo, j1 = j0 + 16, j2 = j0 + 32;
    float s0 = (j0 >= i - WIN && j0 <= i + WIN && j0 < TT) ? acc[0][q] * 0.125f : -INFINITY;
    float s1 = (j1 >= i - WIN && j1 <= i + WIN && j1 < TT) ? acc[1][q] * 0.125f : -INFINITY;
    float s2 = (j2 >= i - WIN && j2 <= i + WIN && j2 < TT) ? acc[2][q] * 0.125f : -INFINITY;
    float m = fmaxf(fmaxf(s0, s1), s2);
#pragma unroll
    for (int off = 8; off; off >>= 1) m = fmaxf(m, __shfl_xor(m, off));
    const float e0 = __expf(s0 - m);
    const float e1 = __expf(s1 - m);
    const float e2 = __expf(s2 - m);
    e[0][q] = e0; e[1][q] = e1; e[2][q] = e2;
    float sum = e0 + e1 + e2;
#pragma unroll
    for (int off = 8; off; off >>= 1) sum += __shfl_xor(sum, off);
    inv[q] = 1.0f / sum;
  }

  const size_t obase = ((size_t)(b * NH + h)) * TT * NC;
#pragma unroll
  for (int q = 0; q < 4; ++q) {
    const int i = i0 + hi * 4 + q;
    int st = i - WIN;
    if (st < 0) st = 0;
    if (st > TT - NC) st = TT - NC;
#pragma unroll
    for (int a = 0; a < 3; ++a) {
      const int c = jb + a * 16 + lo - st;
      if (c >= 0 && c < NC)
        out[obase + (size_t)i * NC + c] = e[a][q] * inv[q];
    }
  }
}

extern "C" void kernel_launch(void* const* d_in, const int* in_sizes, int n_in,
                              void* d_out, int out_size, void* d_ws, size_t ws_size,
                              hipStream_t stream)
{
  const float* query = (const float*)d_in[0];
  const float* key   = (const float*)d_in[1];
  const float* Wq    = (const float*)d_in[2];
  const float* bq    = (const float*)d_in[3];
  const float* Wk    = (const float*)d_in[4];
  const float* bk    = (const float*)d_in[5];
  float* out = (float*)d_out;

  const int B = 4, M = B * TT;      // 8192 rows
  ushort* Wqb = (ushort*)d_ws;                  // 512x512 bf16
  ushort* Wkb = Wqb + (size_t)HH * HH;
  ushort* Qp  = Wkb + (size_t)HH * HH;          // [M,512] bf16 projected
  ushort* Kp  = Qp + (size_t)M * HH;

  cvt_w<<<dim3(256), 256, 0, stream>>>(Wq, Wk, Wqb, Wkb);
  proj_mfma<<<dim3(M / PBM, HH / PBN, 2), 256, 0, stream>>>(
      query, key, Wqb, Wkb, bq, bk, Qp, Kp);
  attn_mfma<<<dim3((M / 16) * NH / 4), 256, 0, stream>>>(Qp, Kp, out);
}

// Round 16
// 33.398 us; speedup vs baseline: 1.2005x; 1.2005x over previous
//
#include <hip/hip_runtime.h>
#include <hip/hip_bf16.h>
#include <math.h>

#define TT 2048
#define HH 512   // hidden = NUM_HEADS*DIM_KEY
#define NH 8
#define DK 64
#define WIN 16
#define NC 33    // 2*WIN+1
#define MT 8192  // B*T rows

typedef __attribute__((ext_vector_type(8))) short bf16x8;
typedef __attribute__((ext_vector_type(4))) float f32x4;

__device__ inline ushort f2bf(float f) {   // RNE float -> bf16 bits
  uint u = __builtin_bit_cast(uint, f);
  return (ushort)((u + 0x7FFFu + ((u >> 16) & 1u)) >> 16);
}
__device__ inline ushort cvt1(float f) {   // compiler cast (v_cvt_pk capable)
  __hip_bfloat16 h = __float2bfloat16(f);
  return __builtin_bit_cast(ushort, h);
}

// ---------------- W fp32 -> bf16 pre-convert (weights only, 2 MB) ---------
__global__ __launch_bounds__(256) void cvt_w(
    const float* __restrict__ Wq, const float* __restrict__ Wk,
    ushort* __restrict__ Wqb, ushort* __restrict__ Wkb)
{
  const int id = blockIdx.x * 256 + threadIdx.x;   // 65536 tasks x 8 elems
  const float* src = (id < 32768) ? Wq : Wk;
  ushort* dst = (id < 32768) ? Wqb : Wkb;
  const int off = (id & 32767) * 8;
  float4 x = *(const float4*)(src + off);
  float4 y = *(const float4*)(src + off + 4);
  union { ushort s[8]; uint4 v; } pk;
  pk.s[0]=cvt1(x.x); pk.s[1]=cvt1(x.y); pk.s[2]=cvt1(x.z); pk.s[3]=cvt1(x.w);
  pk.s[4]=cvt1(y.x); pk.s[5]=cvt1(y.y); pk.s[6]=cvt1(y.z); pk.s[7]=cvt1(y.w);
  *(uint4*)(dst + off) = pk.v;
}

// ============ BALANCED FUSED: proj(Q,K) + windowed attn ====================
// R14 skeleton with its three measured sins fixed:
//  (1) W staged bf16 via global_load_lds (was fp32 reg-staged, 4x redundant)
//  (2) balanced waves: (wr2,wc2) = (w>>2, w&3); each wave owns 5 row-subtiles
//      (160 proj rows / 16 / 2 groups) x 2 col-subtiles -> 10 MFMA/kk for
//      EVERY wave (R14: waves 0-1 did 2x the rest)
//  (3) LDS 52 KB exactly: AQ[64x64]@0, AK[96x64]@4096, WQ[128x64]@10240,
//      WK[128x64]@18432 (ushorts). Phase 2 aliased: QP[64x128]@0,
//      KP[96x128]@8192. 16B-granule XOR swizzle everywhere (verified).
__global__ __launch_bounds__(512, 4) void fused_mha(
    const float* __restrict__ qin, const float* __restrict__ kin,
    const ushort* __restrict__ Wqb, const ushort* __restrict__ Wkb,
    const float* __restrict__ bq, const float* __restrict__ bk,
    float* __restrict__ out)
{
  __shared__ ushort lds[26624];   // 52 KB

  const int m0 = blockIdx.x * 64;       // absolute q-row base
  const int n0 = blockIdx.y * 128;      // output col base (heads 2y, 2y+1)
  const int t  = threadIdx.x;
  const int w  = t >> 6;                // wave 0..7
  const int l  = t & 63;
  const int lr = l & 15;
  const int hi = l >> 4;
  const int swz = lr & 7;
  const int wr2 = w >> 2;               // row-group 0/1 (sub-rows 0-4 / 5-9)
  const int wc2 = w & 3;                // col-group 0..3 (2 col-subtiles)

  f32x4 acc[5][2] = {};

  // =================== phase 1: projection ===================
  for (int k0 = 0; k0 < HH; k0 += 64) {
    // ---- W: 2048 granules bf16 via global_load_lds (issue first) ----
#pragma unroll
    for (int p = 0; p < 4; ++p) {
      const int u2 = p * 512 + t;
      const int lg = (u2 < 1024) ? u2 : u2 - 1024;
      const int r  = lg >> 3;
      const int g  = (lg & 7) ^ (r & 7);
      const ushort* src = ((u2 < 1024) ? Wqb : Wkb) + (size_t)(n0 + r) * HH + k0 + g * 8;
      const int base = (u2 < 1024) ? 10240 : 18432;
      __builtin_amdgcn_global_load_lds(
          (const __attribute__((address_space(1))) uint*)src,
          (__attribute__((address_space(3))) uint*)(lds + base + lg * 8),
          16, 0, 0);
    }
    // ---- A: q 512 + k-halo 768 granules fp32->bf16 (2.5 rounds) ----
#pragma unroll
    for (int p = 0; p < 3; ++p) {
      const int u = p * 512 + t;
      if (p < 2 || t < 256) {
        const float* src; int base, lg;
        if (u < 512) { lg = u; const int r = lg >> 3; src = qin + (size_t)(m0 + r) * HH; base = 0; }
        else         { lg = u - 512; const int r = lg >> 3; int ar = m0 - 16 + r;
                       ar = ar < 0 ? 0 : (ar > MT - 1 ? MT - 1 : ar);
                       src = kin + (size_t)ar * HH; base = 4096; }
        const int rr = lg >> 3;
        const int g  = (lg & 7) ^ (rr & 7);
        const float* gp = src + k0 + g * 8;
        float4 x = ((const float4*)gp)[0], y = ((const float4*)gp)[1];
        union { ushort s[8]; uint4 v; } pk;
        pk.s[0]=cvt1(x.x); pk.s[1]=cvt1(x.y); pk.s[2]=cvt1(x.z); pk.s[3]=cvt1(x.w);
        pk.s[4]=cvt1(y.x); pk.s[5]=cvt1(y.y); pk.s[6]=cvt1(y.z); pk.s[7]=cvt1(y.w);
        *(uint4*)&lds[base + lg * 8] = pk.v;
      }
    }
    __syncthreads();

    // ---- compute: 10 MFMA per kk per wave, all waves equal ----
#pragma unroll
    for (int kk = 0; kk < 64; kk += 32) {
      const int gq = (kk >> 3) + hi;
      bf16x8 bqf[2], bkf[2];
#pragma unroll
      for (int cc = 0; cc < 2; ++cc) {
        const int crow = (wc2 * 2 + cc) * 16 + lr;
        bqf[cc] = *(const bf16x8*)&lds[10240 + crow * 64 + ((gq ^ swz) * 8)];
        bkf[cc] = *(const bf16x8*)&lds[18432 + crow * 64 + ((gq ^ swz) * 8)];
      }
#pragma unroll
      for (int j = 0; j < 5; ++j) {
        const int srow = wr2 * 5 + j;          // 0..9 (0-3 = q, 4-9 = k)
        const bool isq = (srow < 4);
        const int abase = isq ? 0 : 4096;
        const int arow  = (isq ? srow : srow - 4) * 16 + lr;
        bf16x8 af = *(const bf16x8*)&lds[abase + arow * 64 + ((gq ^ swz) * 8)];
#pragma unroll
        for (int cc = 0; cc < 2; ++cc)
          acc[j][cc] = __builtin_amdgcn_mfma_f32_16x16x32_bf16(
              af, isq ? bqf[cc] : bkf[cc], acc[j][cc], 0, 0, 0);
      }
    }
    __syncthreads();
  }

  // ---- epilogue 1: acc (+bias) -> QP/KP LDS (bf16, swizzled scalar) ----
  // C-frag layout (verified): row = hi*4+q_, col = lr (within 16x16 tile).
#pragma unroll
  for (int j = 0; j < 5; ++j) {
    const int srow = wr2 * 5 + j;
    const bool isq = (srow < 4);
    const int pbase = isq ? 0 : 8192;
    const int rowt  = (isq ? srow : srow - 4) * 16;
#pragma unroll
    for (int cc = 0; cc < 2; ++cc) {
      const int c2 = (wc2 * 2 + cc) * 16 + lr;
      const float bc = (isq ? bq : bk)[n0 + c2];
#pragma unroll
      for (int q_ = 0; q_ < 4; ++q_) {
        const int row = rowt + hi * 4 + q_;
        lds[pbase + row * 128 + (((c2 >> 3) ^ (row & 7)) << 3) + (c2 & 7)] =
            f2bf(acc[j][cc][q_] + bc);
      }
    }
  }
  __syncthreads();

  // =================== phase 2: attention (R14 verbatim, verified) =======
  const int s  = w & 3;                 // row sub-tile 0..3
  const int hl = w >> 2;                // head-local 0/1
  const int bb = m0 >> 11;              // batch
  const int ml = m0 & (TT - 1);         // within-batch block row base
  const int i0l = ml + s * 16;          // within-batch tile row base

  int jbt = i0l - WIN;
  if (jbt < 0) jbt = 0;
  if (jbt > TT - NC) jbt = TT - NC;
  const int krb = jbt - ml + 16;        // KP LDS row of window col 0

  f32x4 acc3[3] = {};
#pragma unroll
  for (int kk = 0; kk < 64; kk += 32) {
    const int gc = hl * 8 + (kk >> 3) + hi;   // col granule (head slice)
    const int rowq = s * 16 + lr;
    bf16x8 aq = *(const bf16x8*)&lds[rowq * 128 + ((gc ^ (rowq & 7)) << 3)];
#pragma unroll
    for (int a = 0; a < 3; ++a) {
      const int kr = krb + a * 16 + lr;       // in [0,96)
      bf16x8 bkfr = *(const bf16x8*)&lds[8192 + kr * 128 + ((gc ^ (kr & 7)) << 3)];
      acc3[a] = __builtin_amdgcn_mfma_f32_16x16x32_bf16(aq, bkfr, acc3[a], 0, 0, 0);
    }
  }

  float e[3][4];
  float inv[4];
#pragma unroll
  for (int q_ = 0; q_ < 4; ++q_) {
    const int i = i0l + hi * 4 + q_;
    const int j0 = jbt + lr, j1 = j0 + 16, j2 = j0 + 32;
    float s0 = (j0 >= i - WIN && j0 <= i + WIN && j0 < TT) ? acc3[0][q_] * 0.125f : -INFINITY;
    float s1 = (j1 >= i - WIN && j1 <= i + WIN && j1 < TT) ? acc3[1][q_] * 0.125f : -INFINITY;
    float s2 = (j2 >= i - WIN && j2 <= i + WIN && j2 < TT) ? acc3[2][q_] * 0.125f : -INFINITY;
    float m = fmaxf(fmaxf(s0, s1), s2);
#pragma unroll
    for (int off = 8; off; off >>= 1) m = fmaxf(m, __shfl_xor(m, off));
    const float e0 = __expf(s0 - m);
    const float e1 = __expf(s1 - m);
    const float e2 = __expf(s2 - m);
    e[0][q_] = e0; e[1][q_] = e1; e[2][q_] = e2;
    float sum = e0 + e1 + e2;
#pragma unroll
    for (int off = 8; off; off >>= 1) sum += __shfl_xor(sum, off);
    inv[q_] = 1.0f / sum;
  }

  const int h = blockIdx.y * 2 + hl;
  const size_t obase = ((size_t)(bb * NH + h)) * TT * NC;
#pragma unroll
  for (int q_ = 0; q_ < 4; ++q_) {
    const int i = i0l + hi * 4 + q_;
    int st = i - WIN;
    if (st < 0) st = 0;
    if (st > TT - NC) st = TT - NC;
#pragma unroll
    for (int a = 0; a < 3; ++a) {
      const int c = jbt + a * 16 + lr - st;
      if (c >= 0 && c < NC)
        out[obase + (size_t)i * NC + c] = e[a][q_] * inv[q_];
    }
  }
}

extern "C" void kernel_launch(void* const* d_in, const int* in_sizes, int n_in,
                              void* d_out, int out_size, void* d_ws, size_t ws_size,
                              hipStream_t stream)
{
  const float* query = (const float*)d_in[0];
  const float* key   = (const float*)d_in[1];
  const float* Wq    = (const float*)d_in[2];
  const float* bq    = (const float*)d_in[3];
  const float* Wk    = (const float*)d_in[4];
  const float* bk    = (const float*)d_in[5];
  float* out = (float*)d_out;

  ushort* Wqb = (ushort*)d_ws;                  // 512x512 bf16
  ushort* Wkb = Wqb + (size_t)HH * HH;

  cvt_w<<<dim3(256), 256, 0, stream>>>(Wq, Wk, Wqb, Wkb);
  fused_mha<<<dim3(MT / 64, 4), 512, 0, stream>>>(
      query, key, Wqb, Wkb, bq, bk, out);
}